// Round 17
// baseline (111.109 us; speedup 1.0000x reference)
//
#include <hip/hip_runtime.h>

// Bidirectional LSTM, B=16384 T=512 I=1 H=8, + final linear on [h_f(T-1), h_b(T-1)].
// Backward direction's state at time T-1 is its FIRST scan step -> one step only.
//
// R17 = R16 (zero-DS packed broadcast + fdot2 + 1-rcp gates + ILP-2) with the
// two element streams STAGGERED by half a step:
//    prologue: zB = dots(hB, xB[0])
//    loop:     zA = dots(hA, xA[t]) ; act(B, zB) ; zB = dots(hB, xB[t+1]) ; act(A, zA)
// Every activation cluster (5 v_exp + 2 v_rcp, quarter-rate trans pipe) now has
// the OTHER element's broadcast+dot cluster (~22 regular VALU) adjacent in
// program order -> scheduler fills the trans backpressure (R16 ledger: trans
// apparent cost ~16 cyc vs ~8 cyc pipe rate; 14 trans/SIMD-step = 224 of 419
// busy cyc). Same op count, same deps; only program order changes.

#define LOG2E 1.4426950408889634f

typedef __fp16 h2 __attribute__((ext_vector_type(2)));

// DPP move of a float: ctrl 0x141 = row_half_mirror (8-lane-group preserving)
#define DPPF(v, ctrl) __int_as_float(__builtin_amdgcn_update_dpp(0, __float_as_int(v), (ctrl), 0xF, 0xF, true))
// DPP move of a packed h2 (32-bit): quad_perm broadcast k = k*0x55
#define DPPQH(v, k) __builtin_bit_cast(h2, __builtin_amdgcn_update_dpp(0, __builtin_bit_cast(int, (v)), ((k) * 0x55), 0xF, 0xF, true))

struct Ctx {
    h2 wi2[4], wf2[4], wg2[4], wo2[4];  // pre-scaled, pair-packed to DPP delivery
    float xi, xf, xg, xo;               // input weights, pre-scaled (f32)
    float bi, bf, bg, bo;               // biases, pre-scaled (f32)
};

struct Z4 { float zi, zf, zg, zo; };

__device__ __forceinline__ void load_ctx(Ctx& C, int j, int qp,
    const float* __restrict__ w_ih, const float* __restrict__ w_hh,
    const float* __restrict__ b)
{
    const float si = -LOG2E;           // sigma rows: e = exp2(-z*log2e) = e^-z
    const float sg = 2.0f * LOG2E;     // tanh row:  e = exp2(2z*log2e) = e^{2z}

    const float* ri = w_hh + (size_t)j * 8;
    const float* rf = w_hh + (size_t)(8 + j) * 8;
    const float* rg = w_hh + (size_t)(16 + j) * 8;
    const float* ro = w_hh + (size_t)(24 + j) * 8;
#pragma unroll
    for (int p = 0; p < 4; ++p) {
        int s0 = 4 * qp + p;           // pair element 0: own-quad value
        int s1 = 7 - 4 * qp - p;       // pair element 1: mirrored value
        C.wi2[p] = h2{(__fp16)(ri[s0] * si), (__fp16)(ri[s1] * si)};
        C.wf2[p] = h2{(__fp16)(rf[s0] * si), (__fp16)(rf[s1] * si)};
        C.wg2[p] = h2{(__fp16)(rg[s0] * sg), (__fp16)(rg[s1] * sg)};
        C.wo2[p] = h2{(__fp16)(ro[s0] * si), (__fp16)(ro[s1] * si)};
    }
    C.xi = w_ih[j] * si;      C.bi = b[j] * si;
    C.xf = w_ih[8 + j] * si;  C.bf = b[8 + j] * si;
    C.xg = w_ih[16 + j] * sg; C.bg = b[16 + j] * sg;
    C.xo = w_ih[24 + j] * si; C.bo = b[24 + j] * si;
}

// broadcast + gate dots (all regular VALU + DPP; no trans)
__device__ __forceinline__ Z4 dots(float xt, float h, const Ctx& C)
{
    float hm = DPPF(h, 0x141);                    // h[7-(i&7)] within 8-group
    h2 ph = __builtin_amdgcn_cvt_pkrtz(h, hm);    // {h_l, h_mirror(l)} packed
    h2 p0 = DPPQH(ph, 0);
    h2 p1 = DPPQH(ph, 1);
    h2 p2 = DPPQH(ph, 2);
    h2 p3 = DPPQH(ph, 3);

    Z4 z;
    z.zi = fmaf(xt, C.xi, C.bi);
    z.zf = fmaf(xt, C.xf, C.bf);
    z.zg = fmaf(xt, C.xg, C.bg);
    z.zo = fmaf(xt, C.xo, C.bo);
    z.zi = __builtin_amdgcn_fdot2(p0, C.wi2[0], z.zi, false);
    z.zf = __builtin_amdgcn_fdot2(p0, C.wf2[0], z.zf, false);
    z.zg = __builtin_amdgcn_fdot2(p0, C.wg2[0], z.zg, false);
    z.zo = __builtin_amdgcn_fdot2(p0, C.wo2[0], z.zo, false);
    z.zi = __builtin_amdgcn_fdot2(p1, C.wi2[1], z.zi, false);
    z.zf = __builtin_amdgcn_fdot2(p1, C.wf2[1], z.zf, false);
    z.zg = __builtin_amdgcn_fdot2(p1, C.wg2[1], z.zg, false);
    z.zo = __builtin_amdgcn_fdot2(p1, C.wo2[1], z.zo, false);
    z.zi = __builtin_amdgcn_fdot2(p2, C.wi2[2], z.zi, false);
    z.zf = __builtin_amdgcn_fdot2(p2, C.wf2[2], z.zf, false);
    z.zg = __builtin_amdgcn_fdot2(p2, C.wg2[2], z.zg, false);
    z.zo = __builtin_amdgcn_fdot2(p2, C.wo2[2], z.zo, false);
    z.zi = __builtin_amdgcn_fdot2(p3, C.wi2[3], z.zi, false);
    z.zf = __builtin_amdgcn_fdot2(p3, C.wf2[3], z.zf, false);
    z.zg = __builtin_amdgcn_fdot2(p3, C.wg2[3], z.zg, false);
    z.zo = __builtin_amdgcn_fdot2(p3, C.wo2[3], z.zo, false);
    return z;
}

// activations + state update (trans-heavy: 5 exp + 2 rcp)
__device__ __forceinline__ void act(const Z4& z, float& h, float& cs)
{
    float eg = __builtin_amdgcn_exp2f(z.zg);   // e^{2g}
    float ei = __builtin_amdgcn_exp2f(z.zi);   // e^{-i}
    float ef = __builtin_amdgcn_exp2f(z.zf);   // e^{-f}
    float eo = __builtin_amdgcn_exp2f(z.zo);   // e^{-o}
    float di = 1.0f + ei, df = 1.0f + ef;
    float dg = 1.0f + eg, dz = 1.0f + eo;

    float d12 = di * df;
    float d34 = dg * dz;
    float R = __builtin_amdgcn_rcpf(d12 * d34);
    float t34 = R * d34;                     // 1/(di*df)
    float t12 = R * d12;                     // 1/(dg*dz)
    float sigi = t34 * df;                   // sigma(i)
    float sigf = t34 * di;                   // sigma(f)
    float qg   = t12 * dz;                   // 1/(1+e^{2g})
    float sigo = t12 * dg;                   // sigma(o)

    float tgs = fmaf(-4.0f * LOG2E, qg, 2.0f * LOG2E);   // 2log2e * tanh(g)
    cs = fmaf(sigf, cs, sigi * tgs);
    float ec = __builtin_amdgcn_exp2f(cs);
    float qc = __builtin_amdgcn_rcpf(1.0f + ec);
    h = sigo * fmaf(-2.0f, qc, 1.0f);
}

__global__ __launch_bounds__(256, 1) void bilstm_kernel(
    const float* __restrict__ x, const float* __restrict__ h0, const float* __restrict__ c0,
    const float* __restrict__ w_ih_f, const float* __restrict__ w_hh_f, const float* __restrict__ b_f,
    const float* __restrict__ w_ih_b, const float* __restrict__ w_hh_b, const float* __restrict__ b_b,
    const float* __restrict__ w_lin, const float* __restrict__ b_lin,
    float* __restrict__ out, int B, int T)
{
    int tid = blockIdx.x * 256 + threadIdx.x;
    int p = tid >> 3;                  // element-pair index
    int j = tid & 7;
    int qp = (threadIdx.x >> 2) & 1;   // quad parity within the 8-lane group
    if (p >= (B >> 1)) return;
    int e0 = 2 * p, e1 = 2 * p + 1;

    Ctx Cf;
    load_ctx(Cf, j, qp, w_ih_f, w_hh_f, b_f);

    float hA  = h0[(size_t)e0 * 8 + j];
    float hB  = h0[(size_t)e1 * 8 + j];
    float csA = c0[(size_t)e0 * 8 + j] * (2.0f * LOG2E);
    float csB = c0[(size_t)e1 * 8 + j] * (2.0f * LOG2E);

    const float4* xrA = (const float4*)(x + (size_t)e0 * T);
    const float4* xrB = (const float4*)(x + (size_t)e1 * T);
    int nT4 = T >> 2;
    float4 xvA = xrA[0];
    float4 xvB = xrB[0];

    // half-step stagger: B's dots run one slot ahead of B's act
    Z4 zA, zB;
    zB = dots(xvB.x, hB, Cf);
    for (int t4 = 0; t4 < nT4 - 1; ++t4) {
        float4 nA = xrA[t4 + 1];
        float4 nB = xrB[t4 + 1];
        zA = dots(xvA.x, hA, Cf); act(zB, hB, csB);
        zB = dots(xvB.y, hB, Cf); act(zA, hA, csA);
        zA = dots(xvA.y, hA, Cf); act(zB, hB, csB);
        zB = dots(xvB.z, hB, Cf); act(zA, hA, csA);
        zA = dots(xvA.z, hA, Cf); act(zB, hB, csB);
        zB = dots(xvB.w, hB, Cf); act(zA, hA, csA);
        zA = dots(xvA.w, hA, Cf); act(zB, hB, csB);
        zB = dots(nB.x,  hB, Cf); act(zA, hA, csA);
        xvA = nA; xvB = nB;
    }
    // epilogue: last float4 group (B's stream is one slot ahead)
    zA = dots(xvA.x, hA, Cf); act(zB, hB, csB);
    zB = dots(xvB.y, hB, Cf); act(zA, hA, csA);
    zA = dots(xvA.y, hA, Cf); act(zB, hB, csB);
    zB = dots(xvB.z, hB, Cf); act(zA, hA, csA);
    zA = dots(xvA.z, hA, Cf); act(zB, hB, csB);
    zB = dots(xvB.w, hB, Cf); act(zA, hA, csA);
    zA = dots(xvA.w, hA, Cf); act(zB, hB, csB);
    act(zA, hA, csA);
    float xlastA = xvA.w, xlastB = xvB.w;

    // backward direction: exactly one step on x[:, T-1]
    Ctx Cb;
    load_ctx(Cb, j, qp, w_ih_b, w_hh_b, b_b);
    float hbA  = h0[(size_t)B * 8 + (size_t)e0 * 8 + j];
    float hbB  = h0[(size_t)B * 8 + (size_t)e1 * 8 + j];
    float cbA  = c0[(size_t)B * 8 + (size_t)e0 * 8 + j] * (2.0f * LOG2E);
    float cbB  = c0[(size_t)B * 8 + (size_t)e1 * 8 + j] * (2.0f * LOG2E);
    Z4 zbA = dots(xlastA, hbA, Cb);
    Z4 zbB = dots(xlastB, hbB, Cb);
    act(zbA, hbA, cbA);
    act(zbB, hbB, cbB);

    // final linear per element, reduced across the 8-lane group
    float pA = fmaf(hA, w_lin[j], hbA * w_lin[8 + j]);
    float pB = fmaf(hB, w_lin[j], hbB * w_lin[8 + j]);
    pA += __shfl_xor(pA, 1, 8);
    pB += __shfl_xor(pB, 1, 8);
    pA += __shfl_xor(pA, 2, 8);
    pB += __shfl_xor(pB, 2, 8);
    pA += __shfl_xor(pA, 4, 8);
    pB += __shfl_xor(pB, 4, 8);
    if (j == 0) {
        float bl = b_lin[0];
        out[e0] = pA + bl;
        out[e1] = pB + bl;
    }
}

extern "C" void kernel_launch(void* const* d_in, const int* in_sizes, int n_in,
                              void* d_out, int out_size, void* d_ws, size_t ws_size,
                              hipStream_t stream)
{
    const float* x      = (const float*)d_in[0];
    const float* h0     = (const float*)d_in[1];
    const float* c0     = (const float*)d_in[2];
    const float* w_ih_f = (const float*)d_in[3];
    const float* w_hh_f = (const float*)d_in[4];
    const float* b_f    = (const float*)d_in[5];
    const float* w_ih_b = (const float*)d_in[6];
    const float* w_hh_b = (const float*)d_in[7];
    const float* b_b    = (const float*)d_in[8];
    const float* w_lin  = (const float*)d_in[9];
    const float* b_lin  = (const float*)d_in[10];
    float* out = (float*)d_out;

    int B = in_sizes[1] / 16;   // h0: (2, B, 8)
    int T = in_sizes[0] / B;    // x:  (B, T, 1)

    int threads = (B / 2) * 8;
    dim3 block(256);
    dim3 grid((threads + 255) / 256);
    hipLaunchKernelGGL(bilstm_kernel, grid, block, 0, stream,
                       x, h0, c0, w_ih_f, w_hh_f, b_f, w_ih_b, w_hh_b, b_b,
                       w_lin, b_lin, out, B, T);
}